// Round 4
// baseline (165.310 us; speedup 1.0000x reference)
//
#include <hip/hip_runtime.h>
#include <hip/hip_bf16.h>
#include <math.h>

typedef _Float16 f16x8 __attribute__((ext_vector_type(8)));
typedef _Float16 f16x4 __attribute__((ext_vector_type(4)));
typedef float f32x4 __attribute__((ext_vector_type(4)));

#define MFMA16(a, b, c) __builtin_amdgcn_mfma_f32_16x16x32_f16((a), (b), (c), 0, 0, 0)

// ---------------- kernel 0: W transpose + fp16 hi/lo split -----------------
__global__ __launch_bounds__(256) void wprep_kernel(
    const float* __restrict__ Wq, const float* __restrict__ Wk, const float* __restrict__ Wv,
    _Float16* __restrict__ wt_hi, _Float16* __restrict__ wt_lo) {
  int i = blockIdx.x * 256 + threadIdx.x;
  if (i >= 192 * 384) return;
  int n = i / 384, c = i - n * 384;
  int sel = n >> 6, h = n & 63;
  const float* W = (sel == 0) ? Wq : (sel == 1) ? Wk : Wv;
  float val = W[c * 64 + h];
  _Float16 hi = (_Float16)val;
  wt_hi[i] = hi;
  wt_lo[i] = (_Float16)(val - (float)hi);
}

// ---------------- fused kernel: one block per batch ------------------------
// 8 waves. Wave w owns q-rows {16w..16w+15} U {240-16w..255-16w}.
// Phase A: qkv projection, x loaded straight to registers (no LDS, NO BARRIERS),
// 12 chunks of BK=32, 2-deep prefetch. Phase B: causal flash attn, no barriers.
__global__ __launch_bounds__(512, 2) void fused_kernel(
    const float* __restrict__ x,
    const _Float16* __restrict__ wth, const _Float16* __restrict__ wtl,
    float* __restrict__ out) {
  __shared__ __align__(16) char smem[144384];
  _Float16* kh = (_Float16*)smem;                   // [256][72] f16 (36864 B)
  _Float16* kl = (_Float16*)(smem + 36864);         // [256][72] f16
  _Float16* vT = (_Float16*)(smem + 73728);         // [64][264] f16 (33792 B)
  _Float16* slc = (_Float16*)(smem + 107520);       // 8 x [32][72] f16 (36864 B)

  const int tid = threadIdx.x;
  const int wave = tid >> 6, lane = tid & 63;
  const int g = lane >> 4, l16 = lane & 15;
  const int b = blockIdx.x;
  const int rset[2] = {16 * wave, 240 - 16 * wave};
  const float* xb = x + (size_t)b * 98304;  // 256*384
  _Float16* wsl = slc + wave * 2304;        // this wave's [32][72] slice

  const float K2 = 28.270933f;  // sqrt(384) * log2(e)
  const float NINF = -__builtin_inff();

  // per-set x row pointers (lane-fixed)
  const float* xrow0 = xb + (size_t)(rset[0] + l16) * 384 + g * 8;
  const float* xrow1 = xb + (size_t)(rset[1] + l16) * 384 + g * 8;

  // ---------------- Phase A: projection (barrier-free) ----------------
  f32x4 qa[2][4] = {}, ka[2][4] = {}, va[2][4] = {};
  float4 buf[3][2][2];  // [stage][set][half] — statically indexed (full unroll)

#pragma unroll
  for (int p = 0; p < 2; ++p) {
    buf[p][0][0] = *(const float4*)(xrow0 + p * 32);
    buf[p][0][1] = *(const float4*)(xrow0 + p * 32 + 4);
    buf[p][1][0] = *(const float4*)(xrow1 + p * 32);
    buf[p][1][1] = *(const float4*)(xrow1 + p * 32 + 4);
  }

#pragma unroll
  for (int c = 0; c < 12; ++c) {
    const int kk = c * 32;
    // issue prefetch for chunk c+2
    if (c < 10) {
      buf[(c + 2) % 3][0][0] = *(const float4*)(xrow0 + (c + 2) * 32);
      buf[(c + 2) % 3][0][1] = *(const float4*)(xrow0 + (c + 2) * 32 + 4);
      buf[(c + 2) % 3][1][0] = *(const float4*)(xrow1 + (c + 2) * 32);
      buf[(c + 2) % 3][1][1] = *(const float4*)(xrow1 + (c + 2) * 32 + 4);
    }
    // convert chunk c to f16 hi/lo fragments
    f16x8 ah[2], al[2];
#pragma unroll
    for (int s = 0; s < 2; ++s) {
      float vv[8] = {buf[c % 3][s][0].x, buf[c % 3][s][0].y, buf[c % 3][s][0].z,
                     buf[c % 3][s][0].w, buf[c % 3][s][1].x, buf[c % 3][s][1].y,
                     buf[c % 3][s][1].z, buf[c % 3][s][1].w};
#pragma unroll
      for (int e = 0; e < 8; ++e) {
        _Float16 h = (_Float16)vv[e];
        ah[s][e] = h;
        al[s][e] = (_Float16)(vv[e] - (float)h);
      }
    }
    // compute: W frags loaded once per ct (L1-resident), used by both sets
#pragma unroll
    for (int ct = 0; ct < 4; ++ct) {
      const size_t oq = (size_t)(ct * 16 + l16) * 384 + kk + g * 8;
      f16x8 bqh = *(const f16x8*)&wth[oq];
      f16x8 bql = *(const f16x8*)&wtl[oq];
      f16x8 bkh = *(const f16x8*)&wth[oq + 24576];  // +64*384
      f16x8 bkl = *(const f16x8*)&wtl[oq + 24576];
      f16x8 bvh = *(const f16x8*)&wth[oq + 49152];  // +128*384
#pragma unroll
      for (int s = 0; s < 2; ++s) {
        qa[s][ct] = MFMA16(ah[s], bqh, qa[s][ct]);
        qa[s][ct] = MFMA16(al[s], bqh, qa[s][ct]);
        qa[s][ct] = MFMA16(ah[s], bql, qa[s][ct]);
        ka[s][ct] = MFMA16(ah[s], bkh, ka[s][ct]);
        ka[s][ct] = MFMA16(al[s], bkh, ka[s][ct]);
        ka[s][ct] = MFMA16(ah[s], bkl, ka[s][ct]);
        va[s][ct] = MFMA16(ah[s], bvh, va[s][ct]);  // v: single pass
      }
    }
  }

  // ---- epilogue: k hi/lo + vT to LDS; q redistributed via per-wave slice ----
  // D layout: row = 4g+j (within 16-row tile), col = l16
#pragma unroll
  for (int s = 0; s < 2; ++s) {
    const int rs = rset[s];
#pragma unroll
    for (int ct = 0; ct < 4; ++ct) {
      const int h = ct * 16 + l16;
#pragma unroll
      for (int j = 0; j < 4; ++j) {
        const int row = rs + 4 * g + j;
        float kv = ka[s][ct][j];
        _Float16 khv = (_Float16)kv;
        kh[row * 72 + h] = khv;
        kl[row * 72 + h] = (_Float16)(kv - (float)khv);
        vT[h * 264 + row] = (_Float16)va[s][ct][j];
      }
    }
  }
  f16x8 qhf[2][2], qlf[2][2];  // [set][ks] B-fragments of q
#pragma unroll
  for (int ct = 0; ct < 4; ++ct) {
    const int h = ct * 16 + l16;
#pragma unroll
    for (int j = 0; j < 4; ++j) {
      const int rl = 4 * g + j;
      float qv = qa[0][ct][j];
      _Float16 qh = (_Float16)qv;
      wsl[(rl * 2 + 0) * 72 + h] = qh;
      wsl[(rl * 2 + 1) * 72 + h] = (_Float16)(qv - (float)qh);
    }
  }
  __syncthreads();  // (1) k/v + set0 slice flushed
#pragma unroll
  for (int ks = 0; ks < 2; ++ks) {
    qhf[0][ks] = *(const f16x8*)&wsl[(l16 * 2 + 0) * 72 + ks * 32 + g * 8];
    qlf[0][ks] = *(const f16x8*)&wsl[(l16 * 2 + 1) * 72 + ks * 32 + g * 8];
  }
  __syncthreads();  // (2) set0 reads done before overwrite
#pragma unroll
  for (int ct = 0; ct < 4; ++ct) {
    const int h = ct * 16 + l16;
#pragma unroll
    for (int j = 0; j < 4; ++j) {
      const int rl = 4 * g + j;
      float qv = qa[1][ct][j];
      _Float16 qh = (_Float16)qv;
      wsl[(rl * 2 + 0) * 72 + h] = qh;
      wsl[(rl * 2 + 1) * 72 + h] = (_Float16)(qv - (float)qh);
    }
  }
  __syncthreads();  // (3) set1 slice flushed
#pragma unroll
  for (int ks = 0; ks < 2; ++ks) {
    qhf[1][ks] = *(const f16x8*)&wsl[(l16 * 2 + 0) * 72 + ks * 32 + g * 8];
    qlf[1][ks] = *(const f16x8*)&wsl[(l16 * 2 + 1) * 72 + ks * 32 + g * 8];
  }

  // ---------------- Phase B: causal flash attention (no barriers) ----------
  _Float16* psl = wsl;  // per-wave P slice [32][72]
  float mrun[2] = {NINF, NINF}, srun[2] = {0.f, 0.f};
  f32x4 O[2][4] = {};

  for (int c = 0; c < 4; ++c) {
    const int kb = c * 64;
#pragma unroll
    for (int s = 0; s < 2; ++s) {
      const int rs = rset[s];
      if (kb > rs + 15) continue;  // set inactive for this K-chunk (wave-uniform)
      const int qr = rs + l16;     // this lane's q-row (fixed)
      // QK^T swapped: sa[kt][j] = S[qr][kb+16kt+4g+j]
      f32x4 sa[4] = {};
#pragma unroll
      for (int kt = 0; kt < 4; ++kt) {
        if (kb + 16 * kt > rs + 15) continue;  // fully-masked tile (wave-uniform)
#pragma unroll
        for (int ks = 0; ks < 2; ++ks) {
          const int ko = (kb + 16 * kt + l16) * 72 + ks * 32 + g * 8;
          f16x8 akh = *(const f16x8*)&kh[ko];
          f16x8 akl = *(const f16x8*)&kl[ko];
          sa[kt] = MFMA16(akh, qhf[s][ks], sa[kt]);
          sa[kt] = MFMA16(akl, qhf[s][ks], sa[kt]);
          sa[kt] = MFMA16(akh, qlf[s][ks], sa[kt]);
        }
      }
      // causal mask + chunk max
      float cm = NINF;
#pragma unroll
      for (int kt = 0; kt < 4; ++kt)
#pragma unroll
        for (int j = 0; j < 4; ++j) {
          const int krow = kb + 16 * kt + 4 * g + j;
          float sv = (krow <= qr) ? sa[kt][j] : NINF;
          sa[kt][j] = sv;
          cm = fmaxf(cm, sv);
        }
      cm = fmaxf(cm, __shfl_xor(cm, 16));
      cm = fmaxf(cm, __shfl_xor(cm, 32));
      const float mn = fmaxf(mrun[s], cm);
      const float scl = exp2f(K2 * (mrun[s] - mn));  // 0 on first chunk
      mrun[s] = mn;
      // P = exp(scale*(S-m)) -> f16 slice; sum
      float cs = 0.f;
#pragma unroll
      for (int kt = 0; kt < 4; ++kt)
#pragma unroll
        for (int j = 0; j < 4; ++j) {
          float p = exp2f(K2 * (sa[kt][j] - mn));
          cs += p;
          psl[(s * 16 + l16) * 72 + kt * 16 + 4 * g + j] = (_Float16)p;
        }
      cs += __shfl_xor(cs, 16);
      cs += __shfl_xor(cs, 32);
      srun[s] = srun[s] * scl + cs;
#pragma unroll
      for (int ht = 0; ht < 4; ++ht) O[s][ht] *= scl;
      // make P writes visible to this wave's reads, defeat MFMA hoisting
      asm volatile("s_waitcnt lgkmcnt(0)" ::: "memory");
      __builtin_amdgcn_sched_barrier(0);
      // PV: O^T[h][qr] += v^T[h][s] * P^T[s][qr]
#pragma unroll
      for (int ks2 = 0; ks2 < 2; ++ks2) {
        f16x8 bp = *(const f16x8*)&psl[(s * 16 + l16) * 72 + ks2 * 32 + g * 8];
#pragma unroll
        for (int ht = 0; ht < 4; ++ht) {
          f16x8 av = *(const f16x8*)&vT[(ht * 16 + l16) * 264 + kb + ks2 * 32 + g * 8];
          O[s][ht] = MFMA16(av, bp, O[s][ht]);
        }
      }
    }
  }

  // ---- output: out[qr][h] = O^T[h][qr] / srun ----
#pragma unroll
  for (int s = 0; s < 2; ++s) {
    const int qr = rset[s] + l16;
    const float inv = 1.0f / srun[s];
#pragma unroll
    for (int ht = 0; ht < 4; ++ht) {
      f32x4 r = O[s][ht] * inv;
      *(f32x4*)&out[((size_t)b * 256 + qr) * 64 + ht * 16 + 4 * g] = r;
    }
  }
}

// ---------------------------------------------------------------------------
extern "C" void kernel_launch(void* const* d_in, const int* in_sizes, int n_in,
                              void* d_out, int out_size, void* d_ws, size_t ws_size,
                              hipStream_t stream) {
  const float* x  = (const float*)d_in[0];
  const float* Wq = (const float*)d_in[1];
  const float* Wk = (const float*)d_in[2];
  const float* Wv = (const float*)d_in[3];

  char* ws = (char*)d_ws;
  _Float16* wt_hi = (_Float16*)ws;             // 192*384 f16 = 147456 B
  _Float16* wt_lo = (_Float16*)(ws + 147456);  // 147456 B

  wprep_kernel<<<288, 256, 0, stream>>>(Wq, Wk, Wv, wt_hi, wt_lo);
  fused_kernel<<<512, 512, 0, stream>>>(x, wt_hi, wt_lo, (float*)d_out);
}

// Round 5
// 85.999 us; speedup vs baseline: 1.9222x; 1.9222x over previous
//
#include <hip/hip_runtime.h>
#include <hip/hip_bf16.h>
#include <math.h>

typedef _Float16 f16x8 __attribute__((ext_vector_type(8)));
typedef _Float16 f16x4 __attribute__((ext_vector_type(4)));
typedef float f32x4 __attribute__((ext_vector_type(4)));

#define MFMA16(a, b, c) __builtin_amdgcn_mfma_f32_16x16x32_f16((a), (b), (c), 0, 0, 0)

typedef __attribute__((address_space(3))) char as3_char;
typedef __attribute__((address_space(1))) const char as1_char;
__device__ __forceinline__ void glds16(const void* g, void* l) {
  __builtin_amdgcn_global_load_lds((as1_char*)g, (as3_char*)l, 16, 0, 0);
}

// ---------------- kernel 0: W -> chunked, pre-swizzled f16 hi/lo staging ----
// Wstg: 12 chunks x 1536 segs x 16B. Seg s2 = p*768 + r*4 + gg holds
// WT_p[r][c0*32 + g*8 .. +8] where g = gg ^ ((r>>1)&3)  (bank-spread swizzle).
__global__ __launch_bounds__(256) void wprep_kernel(
    const float* __restrict__ Wq, const float* __restrict__ Wk, const float* __restrict__ Wv,
    _Float16* __restrict__ wstg) {
  int s = blockIdx.x * 256 + threadIdx.x;  // 0..18431
  int c0 = s / 1536, s2 = s % 1536;
  int p = s2 / 768, r = (s2 % 768) / 4, gg = s2 & 3;
  int g = gg ^ ((r >> 1) & 3);
  int sel = r >> 6, h = r & 63;
  const float* W = (sel == 0) ? Wq : (sel == 1) ? Wk : Wv;
  f16x8 o;
#pragma unroll
  for (int e = 0; e < 8; ++e) {
    float val = W[(c0 * 32 + g * 8 + e) * 64 + h];
    _Float16 hi = (_Float16)val;
    o[e] = p ? (_Float16)(val - (float)hi) : hi;
  }
  *(f16x8*)&wstg[(size_t)s * 8] = o;
}

// ---------------- fused kernel: one block per batch ------------------------
// 8 waves. Wave w owns q-rows {16w..16w+15} U {240-16w..255-16w}.
// Phase A: qkv proj. W staged LDS-dbuf via global_load_lds (counted vmcnt,
// raw barriers); x -> registers, 2-chunk-deep prefetch that SURVIVES barriers.
// Phase B: causal flash attention, no barriers (per-wave independent).
__global__ __launch_bounds__(512, 2) void fused_kernel(
    const float* __restrict__ x,
    const _Float16* __restrict__ wstg,
    float* __restrict__ out) {
  __shared__ __align__(16) char smem[156672];
  _Float16* kh = (_Float16*)smem;              // [256][72] f16 (36864 B)
  _Float16* kl = (_Float16*)(smem + 36864);    // [256][72] f16
  _Float16* vT = (_Float16*)(smem + 73728);    // [64][264] f16 (33792 B)
  char* wbuf0 = smem + 107520;                 // W chunk buf (24576 B)
  char* wbuf1 = smem + 132096;                 // W chunk buf (24576 B)
  _Float16* slc = (_Float16*)(smem + 107520);  // ALIAS: 8 x [32][72] (phase B)

  const int tid = threadIdx.x;
  const int wave = tid >> 6, lane = tid & 63;
  const int g = lane >> 4, l16 = lane & 15;
  const int b = blockIdx.x;
  const int rset[2] = {16 * wave, 240 - 16 * wave};
  const float* xb = x + (size_t)b * 98304;  // 256*384
  _Float16* wsl = slc + wave * 2304;        // this wave's private [32][72] slice

  const float K2 = 28.270933f;  // sqrt(384) * log2(e)
  const float NINF = -__builtin_inff();

  // per-set x row pointers (lane-fixed): 32B per chunk each
  const float* xrow0 = xb + (size_t)(rset[0] + l16) * 384 + g * 8;
  const float* xrow1 = xb + (size_t)(rset[1] + l16) * 384 + g * 8;

  // ---------------- Phase A ----------------
  f32x4 qa[2][4] = {}, ka[2][4] = {}, va[2][4] = {};
  float4 buf[3][2][2];  // [stage][set][half], statically indexed (full unroll)

  // prologue: W(0) glds, then x(0), x(1)
#pragma unroll
  for (int i = 0; i < 3; ++i) {
    int seg0 = wave * 192 + i * 64;
    glds16(wstg + (size_t)(seg0 + lane) * 8, wbuf0 + seg0 * 16);
  }
  __builtin_amdgcn_sched_barrier(0);
#pragma unroll
  for (int p = 0; p < 2; ++p) {
    buf[p][0][0] = *(const float4*)(xrow0 + p * 32);
    buf[p][0][1] = *(const float4*)(xrow0 + p * 32 + 4);
    buf[p][1][0] = *(const float4*)(xrow1 + p * 32);
    buf[p][1][1] = *(const float4*)(xrow1 + p * 32 + 4);
  }
  __builtin_amdgcn_sched_barrier(0);
  asm volatile("s_waitcnt vmcnt(4) lgkmcnt(0)" ::: "memory");
  __builtin_amdgcn_s_barrier();
  __builtin_amdgcn_sched_barrier(0);

#pragma unroll
  for (int c = 0; c < 12; ++c) {
    // issue glds for W(c+1) into the other buffer
    if (c < 11) {
      char* nb = ((c + 1) & 1) ? wbuf1 : wbuf0;
      const _Float16* src = wstg + (size_t)(c + 1) * 12288;  // 1536*8 f16
#pragma unroll
      for (int i = 0; i < 3; ++i) {
        int seg0 = wave * 192 + i * 64;
        glds16(src + (size_t)(seg0 + lane) * 8, nb + seg0 * 16);
      }
    }
    __builtin_amdgcn_sched_barrier(0);
    // issue x prefetch for chunk c+2
    if (c < 10) {
      buf[(c + 2) % 3][0][0] = *(const float4*)(xrow0 + (c + 2) * 32);
      buf[(c + 2) % 3][0][1] = *(const float4*)(xrow0 + (c + 2) * 32 + 4);
      buf[(c + 2) % 3][1][0] = *(const float4*)(xrow1 + (c + 2) * 32);
      buf[(c + 2) % 3][1][1] = *(const float4*)(xrow1 + (c + 2) * 32 + 4);
    }
    __builtin_amdgcn_sched_barrier(0);

    // convert chunk c to f16 hi/lo A-fragments
    const char* wb = (c & 1) ? wbuf1 : wbuf0;
    f16x8 ah[2], al[2];
#pragma unroll
    for (int s = 0; s < 2; ++s) {
      float vv[8] = {buf[c % 3][s][0].x, buf[c % 3][s][0].y, buf[c % 3][s][0].z,
                     buf[c % 3][s][0].w, buf[c % 3][s][1].x, buf[c % 3][s][1].y,
                     buf[c % 3][s][1].z, buf[c % 3][s][1].w};
#pragma unroll
      for (int e = 0; e < 8; ++e) {
        _Float16 h = (_Float16)vv[e];
        ah[s][e] = h;
        al[s][e] = (_Float16)(vv[e] - (float)h);
      }
    }
    // compute: B-frags from LDS (swizzled), 56 MFMA per wave
#pragma unroll
    for (int ct = 0; ct < 4; ++ct) {
      const int rq = ct * 16 + l16;        // q row (WT row)
      const int rk = 64 + ct * 16 + l16;   // k row
      const int rv = 128 + ct * 16 + l16;  // v row
      f16x8 bqh = *(const f16x8*)(wb + (0 * 768 + rq * 4 + (g ^ ((rq >> 1) & 3))) * 16);
      f16x8 bql = *(const f16x8*)(wb + (1 * 768 + rq * 4 + (g ^ ((rq >> 1) & 3))) * 16);
      f16x8 bkh = *(const f16x8*)(wb + (0 * 768 + rk * 4 + (g ^ ((rk >> 1) & 3))) * 16);
      f16x8 bkl = *(const f16x8*)(wb + (1 * 768 + rk * 4 + (g ^ ((rk >> 1) & 3))) * 16);
      f16x8 bvh = *(const f16x8*)(wb + (0 * 768 + rv * 4 + (g ^ ((rv >> 1) & 3))) * 16);
#pragma unroll
      for (int s = 0; s < 2; ++s) {
        qa[s][ct] = MFMA16(ah[s], bqh, qa[s][ct]);
        qa[s][ct] = MFMA16(al[s], bqh, qa[s][ct]);
        qa[s][ct] = MFMA16(ah[s], bql, qa[s][ct]);
        ka[s][ct] = MFMA16(ah[s], bkh, ka[s][ct]);
        ka[s][ct] = MFMA16(al[s], bkh, ka[s][ct]);
        ka[s][ct] = MFMA16(ah[s], bkl, ka[s][ct]);
        va[s][ct] = MFMA16(ah[s], bvh, va[s][ct]);  // v: single pass
      }
    }
    // counted drain: W(c+1)+x(c+1) done, x(c+2) stays in flight
    if (c < 10) {
      asm volatile("s_waitcnt vmcnt(4) lgkmcnt(0)" ::: "memory");
    } else if (c == 10) {
      asm volatile("s_waitcnt vmcnt(0) lgkmcnt(0)" ::: "memory");
    } else {
      asm volatile("s_waitcnt lgkmcnt(0)" ::: "memory");
    }
    __builtin_amdgcn_s_barrier();
    __builtin_amdgcn_sched_barrier(0);
  }

  // ---- epilogue: k hi/lo + vT to LDS (cross-wave data) ----
#pragma unroll
  for (int s = 0; s < 2; ++s) {
    const int rs = rset[s];
#pragma unroll
    for (int ct = 0; ct < 4; ++ct) {
      const int h = ct * 16 + l16;
#pragma unroll
      for (int j = 0; j < 4; ++j) {
        const int row = rs + 4 * g + j;
        float kv = ka[s][ct][j];
        _Float16 khv = (_Float16)kv;
        kh[row * 72 + h] = khv;
        kl[row * 72 + h] = (_Float16)(kv - (float)khv);
        vT[h * 264 + row] = (_Float16)va[s][ct][j];
      }
    }
  }
  __syncthreads();  // (a) all W-buf reads done; kv/vT visible -> slc region free

  f16x8 qhf[2][2], qlf[2][2];  // [set][ks] B-fragments of q
#pragma unroll
  for (int ct = 0; ct < 4; ++ct) {
    const int h = ct * 16 + l16;
#pragma unroll
    for (int j = 0; j < 4; ++j) {
      const int rl = 4 * g + j;
      float qv = qa[0][ct][j];
      _Float16 qh = (_Float16)qv;
      wsl[(rl * 2 + 0) * 72 + h] = qh;
      wsl[(rl * 2 + 1) * 72 + h] = (_Float16)(qv - (float)qh);
    }
  }
  __syncthreads();  // (b)
#pragma unroll
  for (int ks = 0; ks < 2; ++ks) {
    qhf[0][ks] = *(const f16x8*)&wsl[(l16 * 2 + 0) * 72 + ks * 32 + g * 8];
    qlf[0][ks] = *(const f16x8*)&wsl[(l16 * 2 + 1) * 72 + ks * 32 + g * 8];
  }
  __syncthreads();  // (c)
#pragma unroll
  for (int ct = 0; ct < 4; ++ct) {
    const int h = ct * 16 + l16;
#pragma unroll
    for (int j = 0; j < 4; ++j) {
      const int rl = 4 * g + j;
      float qv = qa[1][ct][j];
      _Float16 qh = (_Float16)qv;
      wsl[(rl * 2 + 0) * 72 + h] = qh;
      wsl[(rl * 2 + 1) * 72 + h] = (_Float16)(qv - (float)qh);
    }
  }
  __syncthreads();  // (d)
#pragma unroll
  for (int ks = 0; ks < 2; ++ks) {
    qhf[1][ks] = *(const f16x8*)&wsl[(l16 * 2 + 0) * 72 + ks * 32 + g * 8];
    qlf[1][ks] = *(const f16x8*)&wsl[(l16 * 2 + 1) * 72 + ks * 32 + g * 8];
  }
  asm volatile("s_waitcnt lgkmcnt(0)" ::: "memory");
  __builtin_amdgcn_sched_barrier(0);

  // ---------------- Phase B: causal flash attention (no barriers) ----------
  _Float16* psl = wsl;  // per-wave private P slice [32][72]
  float mrun[2] = {NINF, NINF}, srun[2] = {0.f, 0.f};
  f32x4 O[2][4] = {};

  for (int c = 0; c < 4; ++c) {
    const int kb = c * 64;
#pragma unroll
    for (int s = 0; s < 2; ++s) {
      const int rs = rset[s];
      if (kb > rs + 15) continue;  // set inactive (wave-uniform)
      const int qr = rs + l16;     // this lane's q-row (fixed)
      // QK^T swapped: sa[kt][j] = S[qr][kb+16kt+4g+j]
      f32x4 sa[4] = {};
#pragma unroll
      for (int kt = 0; kt < 4; ++kt) {
        if (kb + 16 * kt > rs + 15) continue;  // fully-masked tile (wave-uniform)
#pragma unroll
        for (int ks = 0; ks < 2; ++ks) {
          const int ko = (kb + 16 * kt + l16) * 72 + ks * 32 + g * 8;
          f16x8 akh = *(const f16x8*)&kh[ko];
          f16x8 akl = *(const f16x8*)&kl[ko];
          sa[kt] = MFMA16(akh, qhf[s][ks], sa[kt]);
          sa[kt] = MFMA16(akl, qhf[s][ks], sa[kt]);
          sa[kt] = MFMA16(akh, qlf[s][ks], sa[kt]);
        }
      }
      // causal mask + chunk max
      float cm = NINF;
#pragma unroll
      for (int kt = 0; kt < 4; ++kt)
#pragma unroll
        for (int j = 0; j < 4; ++j) {
          const int krow = kb + 16 * kt + 4 * g + j;
          float sv = (krow <= qr) ? sa[kt][j] : NINF;
          sa[kt][j] = sv;
          cm = fmaxf(cm, sv);
        }
      cm = fmaxf(cm, __shfl_xor(cm, 16));
      cm = fmaxf(cm, __shfl_xor(cm, 32));
      const float mn = fmaxf(mrun[s], cm);
      const float scl = exp2f(K2 * (mrun[s] - mn));  // 0 on first chunk
      mrun[s] = mn;
      // P = exp2(K2*(S-m)) -> f16 slice; sum
      float cs = 0.f;
#pragma unroll
      for (int kt = 0; kt < 4; ++kt)
#pragma unroll
        for (int j = 0; j < 4; ++j) {
          float p = exp2f(K2 * (sa[kt][j] - mn));
          cs += p;
          psl[(s * 16 + l16) * 72 + kt * 16 + 4 * g + j] = (_Float16)p;
        }
      cs += __shfl_xor(cs, 16);
      cs += __shfl_xor(cs, 32);
      srun[s] = srun[s] * scl + cs;
#pragma unroll
      for (int ht = 0; ht < 4; ++ht) O[s][ht] *= scl;
      // make P writes visible to this wave's reads, defeat MFMA hoisting
      asm volatile("s_waitcnt lgkmcnt(0)" ::: "memory");
      __builtin_amdgcn_sched_barrier(0);
      // PV: O^T[h][qr] += v^T[h][s] * P^T[s][qr]
#pragma unroll
      for (int ks2 = 0; ks2 < 2; ++ks2) {
        f16x8 bp = *(const f16x8*)&psl[(s * 16 + l16) * 72 + ks2 * 32 + g * 8];
#pragma unroll
        for (int ht = 0; ht < 4; ++ht) {
          f16x8 av = *(const f16x8*)&vT[(ht * 16 + l16) * 264 + kb + ks2 * 32 + g * 8];
          O[s][ht] = MFMA16(av, bp, O[s][ht]);
        }
      }
    }
  }

  // ---- output: out[qr][h] = O^T[h][qr] / srun ----
#pragma unroll
  for (int s = 0; s < 2; ++s) {
    const int qr = rset[s] + l16;
    const float inv = 1.0f / srun[s];
#pragma unroll
    for (int ht = 0; ht < 4; ++ht) {
      f32x4 r = O[s][ht] * inv;
      *(f32x4*)&out[((size_t)b * 256 + qr) * 64 + ht * 16 + 4 * g] = r;
    }
  }
}

// ---------------------------------------------------------------------------
extern "C" void kernel_launch(void* const* d_in, const int* in_sizes, int n_in,
                              void* d_out, int out_size, void* d_ws, size_t ws_size,
                              hipStream_t stream) {
  const float* x  = (const float*)d_in[0];
  const float* Wq = (const float*)d_in[1];
  const float* Wk = (const float*)d_in[2];
  const float* Wv = (const float*)d_in[3];

  _Float16* wstg = (_Float16*)d_ws;  // 12*1536*16B = 294912 B

  wprep_kernel<<<72, 256, 0, stream>>>(Wq, Wk, Wv, wstg);
  fused_kernel<<<512, 512, 0, stream>>>(x, wstg, (float*)d_out);
}

// Round 7
// 83.626 us; speedup vs baseline: 1.9768x; 1.0284x over previous
//
#include <hip/hip_runtime.h>
#include <hip/hip_bf16.h>
#include <math.h>

typedef _Float16 f16x8 __attribute__((ext_vector_type(8)));
typedef _Float16 f16x4 __attribute__((ext_vector_type(4)));
typedef _Float16 f16x2 __attribute__((ext_vector_type(2)));
typedef __fp16 fp16x2 __attribute__((ext_vector_type(2)));
typedef float f32x4 __attribute__((ext_vector_type(4)));

#define MFMA16(a, b, c) __builtin_amdgcn_mfma_f32_16x16x32_f16((a), (b), (c), 0, 0, 0)

typedef __attribute__((address_space(3))) char as3_char;
typedef __attribute__((address_space(1))) const char as1_char;
__device__ __forceinline__ void glds16(const void* g, void* l) {
  __builtin_amdgcn_global_load_lds((as1_char*)g, (as3_char*)l, 16, 0, 0);
}

union F16x8u { f16x8 v; f16x2 h[4]; };

__device__ __forceinline__ f16x2 pkrtz(float a, float b) {
  fp16x2 r = __builtin_amdgcn_cvt_pkrtz(a, b);
  return __builtin_bit_cast(f16x2, r);
}

// ---------------- kernel 0: W -> chunked, pre-swizzled f16 hi/lo staging ----
// Wstg: 12 chunks x 1536 segs x 16B. Seg s2 = p*768 + r*4 + gg holds
// WT_p[r][c0*32 + g*8 .. +8] where g = gg ^ ((r>>1)&3)  (bank-spread swizzle).
__global__ __launch_bounds__(256) void wprep_kernel(
    const float* __restrict__ Wq, const float* __restrict__ Wk, const float* __restrict__ Wv,
    _Float16* __restrict__ wstg) {
  int s = blockIdx.x * 256 + threadIdx.x;  // 0..18431
  int c0 = s / 1536, s2 = s % 1536;
  int p = s2 / 768, r = (s2 % 768) / 4, gg = s2 & 3;
  int g = gg ^ ((r >> 1) & 3);
  int sel = r >> 6, h = r & 63;
  const float* W = (sel == 0) ? Wq : (sel == 1) ? Wk : Wv;
  f16x8 o;
#pragma unroll
  for (int e = 0; e < 8; ++e) {
    float val = W[(c0 * 32 + g * 8 + e) * 64 + h];
    _Float16 hi = (_Float16)val;
    o[e] = p ? (_Float16)(val - (float)hi) : hi;
  }
  *(f16x8*)&wstg[(size_t)s * 8] = o;
}

// ---------------- fused kernel: one block per batch ------------------------
__global__ __launch_bounds__(512, 2) void fused_kernel(
    const float* __restrict__ x,
    const _Float16* __restrict__ wstg,
    float* __restrict__ out) {
  __shared__ __align__(16) char smem[156672];
  _Float16* kh = (_Float16*)smem;              // [256][72] f16 (36864 B)
  _Float16* kl = (_Float16*)(smem + 36864);    // [256][72] f16
  _Float16* vT = (_Float16*)(smem + 73728);    // [64][264] f16 (33792 B)
  char* wbuf0 = smem + 107520;                 // W chunk buf (24576 B)
  char* wbuf1 = smem + 132096;                 // W chunk buf (24576 B)
  _Float16* slc = (_Float16*)(smem + 107520);  // ALIAS: 8 x [32][72] (epilogue/B)

  const int tid = threadIdx.x;
  const int wave = tid >> 6, lane = tid & 63;
  const int g = lane >> 4, l16 = lane & 15;
  const int b = blockIdx.x;
  const int rset[2] = {16 * wave, 240 - 16 * wave};
  const float* xb = x + (size_t)b * 98304;  // 256*384
  _Float16* wsl = slc + wave * 2304;        // this wave's private [32][72] slice

  const float K2 = 28.270933f;  // sqrt(384) * log2(e)
  const float NINF = -__builtin_inff();

  const float* xrow0 = xb + (size_t)(rset[0] + l16) * 384 + g * 8;
  const float* xrow1 = xb + (size_t)(rset[1] + l16) * 384 + g * 8;

  // ---------------- Phase A ----------------
  f32x4 qa[2][4] = {}, ka[2][4] = {}, va[2][4] = {};
  float4 buf[3][2][2];  // [stage][set][half], statically indexed (full unroll)

  // prologue: W(0) glds, then x(0), x(1)
#pragma unroll
  for (int i = 0; i < 3; ++i) {
    int seg0 = wave * 192 + i * 64;
    glds16(wstg + (size_t)(seg0 + lane) * 8, wbuf0 + seg0 * 16);
  }
  __builtin_amdgcn_sched_barrier(0);
#pragma unroll
  for (int p = 0; p < 2; ++p) {
    buf[p][0][0] = *(const float4*)(xrow0 + p * 32);
    buf[p][0][1] = *(const float4*)(xrow0 + p * 32 + 4);
    buf[p][1][0] = *(const float4*)(xrow1 + p * 32);
    buf[p][1][1] = *(const float4*)(xrow1 + p * 32 + 4);
  }
  __builtin_amdgcn_sched_barrier(0);
  asm volatile("s_waitcnt vmcnt(4) lgkmcnt(0)" ::: "memory");
  __builtin_amdgcn_s_barrier();
  __builtin_amdgcn_sched_barrier(0);

#pragma unroll
  for (int c = 0; c < 12; ++c) {
    // issue glds for W(c+1) into the other buffer
    if (c < 11) {
      char* nb = ((c + 1) & 1) ? wbuf1 : wbuf0;
      const _Float16* src = wstg + (size_t)(c + 1) * 12288;  // 1536*8 f16
#pragma unroll
      for (int i = 0; i < 3; ++i) {
        int seg0 = wave * 192 + i * 64;
        glds16(src + (size_t)(seg0 + lane) * 8, nb + seg0 * 16);
      }
    }
    __builtin_amdgcn_sched_barrier(0);
    // issue x prefetch for chunk c+2
    if (c < 10) {
      buf[(c + 2) % 3][0][0] = *(const float4*)(xrow0 + (c + 2) * 32);
      buf[(c + 2) % 3][0][1] = *(const float4*)(xrow0 + (c + 2) * 32 + 4);
      buf[(c + 2) % 3][1][0] = *(const float4*)(xrow1 + (c + 2) * 32);
      buf[(c + 2) % 3][1][1] = *(const float4*)(xrow1 + (c + 2) * 32 + 4);
    }
    __builtin_amdgcn_sched_barrier(0);

    // convert chunk c to f16 hi/lo A-fragments (packed cvt)
    const char* wb = (c & 1) ? wbuf1 : wbuf0;
    f16x8 ah[2], al[2];
#pragma unroll
    for (int s = 0; s < 2; ++s) {
      float vv[8] = {buf[c % 3][s][0].x, buf[c % 3][s][0].y, buf[c % 3][s][0].z,
                     buf[c % 3][s][0].w, buf[c % 3][s][1].x, buf[c % 3][s][1].y,
                     buf[c % 3][s][1].z, buf[c % 3][s][1].w};
      F16x8u uh, ul;
#pragma unroll
      for (int k2 = 0; k2 < 4; ++k2) {
        float a = vv[2 * k2], bb = vv[2 * k2 + 1];
        f16x2 hp = pkrtz(a, bb);
        uh.h[k2] = hp;
        ul.h[k2] = pkrtz(a - (float)hp[0], bb - (float)hp[1]);
      }
      ah[s] = uh.v;
      al[s] = ul.v;
    }
    // compute: B-frags from LDS (swizzled), 56 MFMA per wave
#pragma unroll
    for (int ct = 0; ct < 4; ++ct) {
      const int rq = ct * 16 + l16;        // q row (WT row)
      const int rk = 64 + ct * 16 + l16;   // k row
      const int rv = 128 + ct * 16 + l16;  // v row
      f16x8 bqh = *(const f16x8*)(wb + (0 * 768 + rq * 4 + (g ^ ((rq >> 1) & 3))) * 16);
      f16x8 bql = *(const f16x8*)(wb + (1 * 768 + rq * 4 + (g ^ ((rq >> 1) & 3))) * 16);
      f16x8 bkh = *(const f16x8*)(wb + (0 * 768 + rk * 4 + (g ^ ((rk >> 1) & 3))) * 16);
      f16x8 bkl = *(const f16x8*)(wb + (1 * 768 + rk * 4 + (g ^ ((rk >> 1) & 3))) * 16);
      f16x8 bvh = *(const f16x8*)(wb + (0 * 768 + rv * 4 + (g ^ ((rv >> 1) & 3))) * 16);
      __builtin_amdgcn_s_setprio(1);
#pragma unroll
      for (int s = 0; s < 2; ++s) {
        qa[s][ct] = MFMA16(ah[s], bqh, qa[s][ct]);
        qa[s][ct] = MFMA16(al[s], bqh, qa[s][ct]);
        qa[s][ct] = MFMA16(ah[s], bql, qa[s][ct]);
        ka[s][ct] = MFMA16(ah[s], bkh, ka[s][ct]);
        ka[s][ct] = MFMA16(al[s], bkh, ka[s][ct]);
        ka[s][ct] = MFMA16(ah[s], bkl, ka[s][ct]);
        va[s][ct] = MFMA16(ah[s], bvh, va[s][ct]);  // v: single pass
      }
      __builtin_amdgcn_s_setprio(0);
    }
    // counted drain: W(c+1)+x(c+1) done, x(c+2) stays in flight
    if (c < 10) {
      asm volatile("s_waitcnt vmcnt(4) lgkmcnt(0)" ::: "memory");
    } else if (c == 10) {
      asm volatile("s_waitcnt vmcnt(0) lgkmcnt(0)" ::: "memory");
    } else {
      asm volatile("s_waitcnt lgkmcnt(0)" ::: "memory");
    }
    __builtin_amdgcn_s_barrier();
    __builtin_amdgcn_sched_barrier(0);
  }

  // ---- epilogue: k hi/lo + vT to LDS (cross-wave data) ----
#pragma unroll
  for (int s = 0; s < 2; ++s) {
    const int rs = rset[s];
#pragma unroll
    for (int ct = 0; ct < 4; ++ct) {
      const int h = ct * 16 + l16;
#pragma unroll
      for (int j = 0; j < 4; ++j) {
        const int row = rs + 4 * g + j;
        float kv = ka[s][ct][j];
        _Float16 khv = (_Float16)kv;
        kh[row * 72 + h] = khv;
        kl[row * 72 + h] = (_Float16)(kv - (float)khv);
        vT[h * 264 + row] = (_Float16)va[s][ct][j];
      }
    }
  }
  __syncthreads();  // (a) all W-buf reads done; kv/vT visible -> slc region free

  f16x8 qhf[2][2], qlf[2][2];  // [set][ks] B-fragments of q
#pragma unroll
  for (int ct = 0; ct < 4; ++ct) {
    const int h = ct * 16 + l16;
#pragma unroll
    for (int j = 0; j < 4; ++j) {
      const int rl = 4 * g + j;
      float qv = qa[0][ct][j];
      _Float16 qh = (_Float16)qv;
      wsl[(rl * 2 + 0) * 72 + h] = qh;
      wsl[(rl * 2 + 1) * 72 + h] = (_Float16)(qv - (float)qh);
    }
  }
  __syncthreads();  // (b)
#pragma unroll
  for (int ks = 0; ks < 2; ++ks) {
    qhf[0][ks] = *(const f16x8*)&wsl[(l16 * 2 + 0) * 72 + ks * 32 + g * 8];
    qlf[0][ks] = *(const f16x8*)&wsl[(l16 * 2 + 1) * 72 + ks * 32 + g * 8];
  }
  __syncthreads();  // (c)
#pragma unroll
  for (int ct = 0; ct < 4; ++ct) {
    const int h = ct * 16 + l16;
#pragma unroll
    for (int j = 0; j < 4; ++j) {
      const int rl = 4 * g + j;
      float qv = qa[1][ct][j];
      _Float16 qh = (_Float16)qv;
      wsl[(rl * 2 + 0) * 72 + h] = qh;
      wsl[(rl * 2 + 1) * 72 + h] = (_Float16)(qv - (float)qh);
    }
  }
  __syncthreads();  // (d)
#pragma unroll
  for (int ks = 0; ks < 2; ++ks) {
    qhf[1][ks] = *(const f16x8*)&wsl[(l16 * 2 + 0) * 72 + ks * 32 + g * 8];
    qlf[1][ks] = *(const f16x8*)&wsl[(l16 * 2 + 1) * 72 + ks * 32 + g * 8];
  }
  asm volatile("s_waitcnt lgkmcnt(0)" ::: "memory");
  __builtin_amdgcn_sched_barrier(0);

  // ---------------- Phase B: causal flash attention (no barriers) ----------
  // Merged sets: kh/kl and vT fragments are set-independent -> read once,
  // feed both sets' MFMAs.
  _Float16* psl = wsl;  // per-wave private P slice [32][72]
  float mrun[2] = {NINF, NINF}, srun[2] = {0.f, 0.f};
  f32x4 O[2][4] = {};
  const int rs0 = rset[0], rs1 = rset[1];
  const int qr0 = rs0 + l16, qr1 = rs1 + l16;

  for (int c = 0; c < 4; ++c) {
    const int kb = c * 64;
    const bool a0 = (kb <= rs0 + 15);  // wave-uniform
    const bool a1 = (kb <= rs1 + 15);  // wave-uniform
    if (!a0 && !a1) continue;
    f32x4 s0[4] = {}, s1[4] = {};
#pragma unroll
    for (int kt = 0; kt < 4; ++kt) {
      const int kr = kb + 16 * kt;
      const bool t0 = a0 && (kr <= rs0 + 15);
      const bool t1 = a1 && (kr <= rs1 + 15);
      if (!t0 && !t1) continue;
#pragma unroll
      for (int ks = 0; ks < 2; ++ks) {
        const int ko = (kr + l16) * 72 + ks * 32 + g * 8;
        f16x8 akh = *(const f16x8*)&kh[ko];
        f16x8 akl = *(const f16x8*)&kl[ko];
        __builtin_amdgcn_s_setprio(1);
        if (t0) {
          s0[kt] = MFMA16(akh, qhf[0][ks], s0[kt]);
          s0[kt] = MFMA16(akl, qhf[0][ks], s0[kt]);
          s0[kt] = MFMA16(akh, qlf[0][ks], s0[kt]);
        }
        if (t1) {
          s1[kt] = MFMA16(akh, qhf[1][ks], s1[kt]);
          s1[kt] = MFMA16(akl, qhf[1][ks], s1[kt]);
          s1[kt] = MFMA16(akh, qlf[1][ks], s1[kt]);
        }
        __builtin_amdgcn_s_setprio(0);
      }
    }
    // ---- softmax per set ----
    if (a0) {
      float cm = NINF;
#pragma unroll
      for (int kt = 0; kt < 4; ++kt)
#pragma unroll
        for (int j = 0; j < 4; ++j) {
          const int krow = kb + 16 * kt + 4 * g + j;
          float sv = (krow <= qr0) ? s0[kt][j] : NINF;
          s0[kt][j] = sv;
          cm = fmaxf(cm, sv);
        }
      cm = fmaxf(cm, __shfl_xor(cm, 16));
      cm = fmaxf(cm, __shfl_xor(cm, 32));
      const float mn = fmaxf(mrun[0], cm);
      const float scl = exp2f(K2 * (mrun[0] - mn));
      mrun[0] = mn;
      float cs = 0.f;
#pragma unroll
      for (int kt = 0; kt < 4; ++kt)
#pragma unroll
        for (int j = 0; j < 4; ++j) {
          float p = exp2f(K2 * (s0[kt][j] - mn));
          cs += p;
          psl[l16 * 72 + kt * 16 + 4 * g + j] = (_Float16)p;
        }
      cs += __shfl_xor(cs, 16);
      cs += __shfl_xor(cs, 32);
      srun[0] = srun[0] * scl + cs;
#pragma unroll
      for (int ht = 0; ht < 4; ++ht) O[0][ht] *= scl;
    }
    if (a1) {
      float cm = NINF;
#pragma unroll
      for (int kt = 0; kt < 4; ++kt)
#pragma unroll
        for (int j = 0; j < 4; ++j) {
          const int krow = kb + 16 * kt + 4 * g + j;
          float sv = (krow <= qr1) ? s1[kt][j] : NINF;
          s1[kt][j] = sv;
          cm = fmaxf(cm, sv);
        }
      cm = fmaxf(cm, __shfl_xor(cm, 16));
      cm = fmaxf(cm, __shfl_xor(cm, 32));
      const float mn = fmaxf(mrun[1], cm);
      const float scl = exp2f(K2 * (mrun[1] - mn));
      mrun[1] = mn;
      float cs = 0.f;
#pragma unroll
      for (int kt = 0; kt < 4; ++kt)
#pragma unroll
        for (int j = 0; j < 4; ++j) {
          float p = exp2f(K2 * (s1[kt][j] - mn));
          cs += p;
          psl[(16 + l16) * 72 + kt * 16 + 4 * g + j] = (_Float16)p;
        }
      cs += __shfl_xor(cs, 16);
      cs += __shfl_xor(cs, 32);
      srun[1] = srun[1] * scl + cs;
#pragma unroll
      for (int ht = 0; ht < 4; ++ht) O[1][ht] *= scl;
    }
    // make P writes visible to this wave's reads, defeat MFMA hoisting
    asm volatile("s_waitcnt lgkmcnt(0)" ::: "memory");
    __builtin_amdgcn_sched_barrier(0);
    // ---- PV with shared vT reads ----
#pragma unroll
    for (int ks2 = 0; ks2 < 2; ++ks2) {
      f16x8 bp0 = {}, bp1 = {};
      if (a0) bp0 = *(const f16x8*)&psl[l16 * 72 + ks2 * 32 + g * 8];
      if (a1) bp1 = *(const f16x8*)&psl[(16 + l16) * 72 + ks2 * 32 + g * 8];
#pragma unroll
      for (int ht = 0; ht < 4; ++ht) {
        f16x8 av = *(const f16x8*)&vT[(ht * 16 + l16) * 264 + kb + ks2 * 32 + g * 8];
        __builtin_amdgcn_s_setprio(1);
        if (a0) O[0][ht] = MFMA16(av, bp0, O[0][ht]);
        if (a1) O[1][ht] = MFMA16(av, bp1, O[1][ht]);
        __builtin_amdgcn_s_setprio(0);
      }
    }
  }

  // ---- output: out[qr][h] = O^T[h][qr] / srun ----
#pragma unroll
  for (int s = 0; s < 2; ++s) {
    const int qr = rset[s] + l16;
    const float inv = 1.0f / srun[s];
#pragma unroll
    for (int ht = 0; ht < 4; ++ht) {
      f32x4 r = O[s][ht] * inv;
      *(f32x4*)&out[((size_t)b * 256 + qr) * 64 + ht * 16 + 4 * g] = r;
    }
  }
}

// ---------------------------------------------------------------------------
extern "C" void kernel_launch(void* const* d_in, const int* in_sizes, int n_in,
                              void* d_out, int out_size, void* d_ws, size_t ws_size,
                              hipStream_t stream) {
  const float* x  = (const float*)d_in[0];
  const float* Wq = (const float*)d_in[1];
  const float* Wk = (const float*)d_in[2];
  const float* Wv = (const float*)d_in[3];

  _Float16* wstg = (_Float16*)d_ws;  // 12*1536*16B = 294912 B

  wprep_kernel<<<72, 256, 0, stream>>>(Wq, Wk, Wv, wstg);
  fused_kernel<<<512, 512, 0, stream>>>(x, wstg, (float*)d_out);
}

// Round 8
// 81.635 us; speedup vs baseline: 2.0250x; 1.0244x over previous
//
#include <hip/hip_runtime.h>
#include <hip/hip_bf16.h>
#include <math.h>

typedef _Float16 f16x8 __attribute__((ext_vector_type(8)));
typedef _Float16 f16x4 __attribute__((ext_vector_type(4)));
typedef _Float16 f16x2 __attribute__((ext_vector_type(2)));
typedef __fp16 fp16x2 __attribute__((ext_vector_type(2)));
typedef float f32x4 __attribute__((ext_vector_type(4)));

#define MFMA16(a, b, c) __builtin_amdgcn_mfma_f32_16x16x32_f16((a), (b), (c), 0, 0, 0)

typedef __attribute__((address_space(3))) char as3_char;
typedef __attribute__((address_space(1))) const char as1_char;
__device__ __forceinline__ void glds16(const void* g, void* l) {
  __builtin_amdgcn_global_load_lds((as1_char*)g, (as3_char*)l, 16, 0, 0);
}

union F16x8u { f16x8 v; f16x2 h[4]; };

__device__ __forceinline__ f16x2 pkrtz(float a, float b) {
  fp16x2 r = __builtin_amdgcn_cvt_pkrtz(a, b);
  return __builtin_bit_cast(f16x2, r);
}

// ---------------- kernel 0: W -> chunked, pre-swizzled f16 hi/lo staging ----
// Wstg: 12 chunks x 1536 segs x 16B. Seg s2 = p*768 + r*4 + gg holds
// WT_p[r][c0*32 + g*8 .. +8] where g = gg ^ ((r>>1)&3)  (bank-spread swizzle).
__global__ __launch_bounds__(256) void wprep_kernel(
    const float* __restrict__ Wq, const float* __restrict__ Wk, const float* __restrict__ Wv,
    _Float16* __restrict__ wstg) {
  int s = blockIdx.x * 256 + threadIdx.x;  // 0..18431
  int c0 = s / 1536, s2 = s % 1536;
  int p = s2 / 768, r = (s2 % 768) / 4, gg = s2 & 3;
  int g = gg ^ ((r >> 1) & 3);
  int sel = r >> 6, h = r & 63;
  const float* W = (sel == 0) ? Wq : (sel == 1) ? Wk : Wv;
  f16x8 o;
#pragma unroll
  for (int e = 0; e < 8; ++e) {
    float val = W[(c0 * 32 + g * 8 + e) * 64 + h];
    _Float16 hi = (_Float16)val;
    o[e] = p ? (_Float16)(val - (float)hi) : hi;
  }
  *(f16x8*)&wstg[(size_t)s * 8] = o;
}

// ---------------- fused kernel: one block per batch, 16 waves --------------
// Wave w owns q-rows 16w..16w+15. 4 waves/SIMD (the latency-hiding fix).
// Phase A: qkv proj, W LDS-dbuf via glds (counted vmcnt), x in regs 2-deep.
// Phase B: causal flash attention, barrier-free, per-SIMD work balanced.
__global__ __launch_bounds__(1024) void fused_kernel(
    const float* __restrict__ x,
    const _Float16* __restrict__ wstg,
    float* __restrict__ out) {
  __shared__ __align__(16) char smem[156672];
  _Float16* kh = (_Float16*)smem;              // [256][72] f16 (36864 B)
  _Float16* kl = (_Float16*)(smem + 36864);    // [256][72] f16
  _Float16* vT = (_Float16*)(smem + 73728);    // [64][264] f16 (33792 B)
  char* wbuf0 = smem + 107520;                 // W chunk buf (24576 B)
  char* wbuf1 = smem + 132096;                 // W chunk buf (24576 B)
  _Float16* slc = (_Float16*)(smem + 107520);  // ALIAS (dead after phase A)

  const int tid = threadIdx.x;
  const int wave = tid >> 6, lane = tid & 63;
  const int g = lane >> 4, l16 = lane & 15;
  const int b = blockIdx.x;
  const int rs = 16 * wave;       // this wave's q-row set
  const int qr = rs + l16;        // this lane's q-row
  const float* xb = x + (size_t)b * 98304;  // 256*384

  const float K2 = 28.270933f;  // sqrt(384) * log2(e)
  const float NINF = -__builtin_inff();

  const float* xrow = xb + (size_t)qr * 384 + g * 8;  // 32B per chunk

  // ---------------- Phase A ----------------
  f32x4 qa[4] = {}, ka[4] = {}, va[4] = {};
  float4 buf[3][2];  // [stage][half], statically indexed (full unroll)

  // prologue: W(0) glds (waves 0-11), then x(0), x(1)
  if (wave < 12) {
#pragma unroll
    for (int i = 0; i < 2; ++i) {
      int seg0 = wave * 128 + i * 64;
      glds16(wstg + (size_t)(seg0 + lane) * 8, wbuf0 + seg0 * 16);
    }
  }
  __builtin_amdgcn_sched_barrier(0);
#pragma unroll
  for (int p = 0; p < 2; ++p) {
    buf[p][0] = *(const float4*)(xrow + p * 32);
    buf[p][1] = *(const float4*)(xrow + p * 32 + 4);
  }
  __builtin_amdgcn_sched_barrier(0);
  asm volatile("s_waitcnt vmcnt(2) lgkmcnt(0)" ::: "memory");
  __builtin_amdgcn_s_barrier();
  __builtin_amdgcn_sched_barrier(0);

#pragma unroll
  for (int c = 0; c < 12; ++c) {
    // issue glds for W(c+1) into the other buffer (waves 0-11)
    if (wave < 12 && c < 11) {
      char* nb = ((c + 1) & 1) ? wbuf1 : wbuf0;
      const _Float16* src = wstg + (size_t)(c + 1) * 12288;  // 1536*8 f16
#pragma unroll
      for (int i = 0; i < 2; ++i) {
        int seg0 = wave * 128 + i * 64;
        glds16(src + (size_t)(seg0 + lane) * 8, nb + seg0 * 16);
      }
    }
    __builtin_amdgcn_sched_barrier(0);
    // issue x prefetch for chunk c+2
    if (c < 10) {
      buf[(c + 2) % 3][0] = *(const float4*)(xrow + (c + 2) * 32);
      buf[(c + 2) % 3][1] = *(const float4*)(xrow + (c + 2) * 32 + 4);
    }
    __builtin_amdgcn_sched_barrier(0);

    // convert chunk c to f16 hi/lo A-fragments (packed cvt)
    const char* wb = (c & 1) ? wbuf1 : wbuf0;
    f16x8 ah, al;
    {
      float vv[8] = {buf[c % 3][0].x, buf[c % 3][0].y, buf[c % 3][0].z,
                     buf[c % 3][0].w, buf[c % 3][1].x, buf[c % 3][1].y,
                     buf[c % 3][1].z, buf[c % 3][1].w};
      F16x8u uh, ul;
#pragma unroll
      for (int k2 = 0; k2 < 4; ++k2) {
        float a = vv[2 * k2], bb = vv[2 * k2 + 1];
        f16x2 hp = pkrtz(a, bb);
        uh.h[k2] = hp;
        ul.h[k2] = pkrtz(a - (float)hp[0], bb - (float)hp[1]);
      }
      ah = uh.v;
      al = ul.v;
    }
    // compute: B-frags from LDS (swizzled), 28 MFMA per wave
#pragma unroll
    for (int ct = 0; ct < 4; ++ct) {
      const int rq = ct * 16 + l16;        // q row (WT row)
      const int rk = 64 + ct * 16 + l16;   // k row
      const int rv = 128 + ct * 16 + l16;  // v row
      f16x8 bqh = *(const f16x8*)(wb + (0 * 768 + rq * 4 + (g ^ ((rq >> 1) & 3))) * 16);
      f16x8 bql = *(const f16x8*)(wb + (1 * 768 + rq * 4 + (g ^ ((rq >> 1) & 3))) * 16);
      f16x8 bkh = *(const f16x8*)(wb + (0 * 768 + rk * 4 + (g ^ ((rk >> 1) & 3))) * 16);
      f16x8 bkl = *(const f16x8*)(wb + (1 * 768 + rk * 4 + (g ^ ((rk >> 1) & 3))) * 16);
      f16x8 bvh = *(const f16x8*)(wb + (0 * 768 + rv * 4 + (g ^ ((rv >> 1) & 3))) * 16);
      __builtin_amdgcn_s_setprio(1);
      qa[ct] = MFMA16(ah, bqh, qa[ct]);
      qa[ct] = MFMA16(al, bqh, qa[ct]);
      qa[ct] = MFMA16(ah, bql, qa[ct]);
      ka[ct] = MFMA16(ah, bkh, ka[ct]);
      ka[ct] = MFMA16(al, bkh, ka[ct]);
      ka[ct] = MFMA16(ah, bkl, ka[ct]);
      va[ct] = MFMA16(ah, bvh, va[ct]);  // v: single pass
      __builtin_amdgcn_s_setprio(0);
    }
    // counted drain: x(c+1)+W(c+1) done, x(c+2) stays in flight (all waves)
    if (c < 10) {
      asm volatile("s_waitcnt vmcnt(2) lgkmcnt(0)" ::: "memory");
    } else if (c == 10) {
      asm volatile("s_waitcnt vmcnt(0) lgkmcnt(0)" ::: "memory");
    } else {
      asm volatile("s_waitcnt lgkmcnt(0)" ::: "memory");
    }
    __builtin_amdgcn_s_barrier();
    __builtin_amdgcn_sched_barrier(0);
  }

  // ---- epilogue: k hi/lo + vT to LDS (cross-wave data) ----
#pragma unroll
  for (int ct = 0; ct < 4; ++ct) {
    const int h = ct * 16 + l16;
#pragma unroll
    for (int j = 0; j < 4; ++j) {
      const int row = rs + 4 * g + j;
      float kv = ka[ct][j];
      _Float16 khv = (_Float16)kv;
      kh[row * 72 + h] = khv;
      kl[row * 72 + h] = (_Float16)(kv - (float)khv);
      vT[h * 264 + row] = (_Float16)va[ct][j];
    }
  }
  __syncthreads();  // (a) W-buf reads done everywhere; slc region free

  // ---- q redistribution via slc, two 8-wave rounds ----
  _Float16* myq = slc + (wave & 7) * 2304;  // [32][72] f16 slice
  f16x8 qhf[2], qlf[2];
#pragma unroll
  for (int rnd = 0; rnd < 2; ++rnd) {
    if ((wave >> 3) == rnd) {
#pragma unroll
      for (int ct = 0; ct < 4; ++ct) {
        const int h = ct * 16 + l16;
#pragma unroll
        for (int j = 0; j < 4; ++j) {
          const int rl = 4 * g + j;
          float qv = qa[ct][j];
          _Float16 qh = (_Float16)qv;
          myq[(rl * 2 + 0) * 72 + h] = qh;
          myq[(rl * 2 + 1) * 72 + h] = (_Float16)(qv - (float)qh);
        }
      }
    }
    __syncthreads();
    if ((wave >> 3) == rnd) {
#pragma unroll
      for (int ks = 0; ks < 2; ++ks) {
        qhf[ks] = *(const f16x8*)&myq[(l16 * 2 + 0) * 72 + ks * 32 + g * 8];
        qlf[ks] = *(const f16x8*)&myq[(l16 * 2 + 1) * 72 + ks * 32 + g * 8];
      }
    }
    __syncthreads();
  }
  asm volatile("s_waitcnt lgkmcnt(0)" ::: "memory");
  __builtin_amdgcn_sched_barrier(0);

  // ---------------- Phase B: causal flash attention (no barriers) ----------
  // Per-SIMD balanced: SIMD s hosts waves {s,s+4,s+8,s+12} = 1+2+3+4 chunks.
  _Float16* psl = slc + wave * 1152;  // per-wave private P slice [16][72]
  float mrun = NINF, srun = 0.f;
  f32x4 O[4] = {};

  for (int c = 0; c < 4; ++c) {
    const int kb = c * 64;
    if (kb > rs + 15) continue;  // wave-uniform
    // QK^T swapped: sa[kt][j] = S[qr][kb+16kt+4g+j]
    f32x4 sa[4] = {};
#pragma unroll
    for (int kt = 0; kt < 4; ++kt) {
      const int kr = kb + 16 * kt;
      if (kr > rs + 15) continue;  // fully-masked tile (wave-uniform)
#pragma unroll
      for (int ks = 0; ks < 2; ++ks) {
        const int ko = (kr + l16) * 72 + ks * 32 + g * 8;
        f16x8 akh = *(const f16x8*)&kh[ko];
        f16x8 akl = *(const f16x8*)&kl[ko];
        __builtin_amdgcn_s_setprio(1);
        sa[kt] = MFMA16(akh, qhf[ks], sa[kt]);
        sa[kt] = MFMA16(akl, qhf[ks], sa[kt]);
        sa[kt] = MFMA16(akh, qlf[ks], sa[kt]);
        __builtin_amdgcn_s_setprio(0);
      }
    }
    // causal mask + chunk max
    float cm = NINF;
#pragma unroll
    for (int kt = 0; kt < 4; ++kt)
#pragma unroll
      for (int j = 0; j < 4; ++j) {
        const int krow = kb + 16 * kt + 4 * g + j;
        float sv = (krow <= qr) ? sa[kt][j] : NINF;
        sa[kt][j] = sv;
        cm = fmaxf(cm, sv);
      }
    cm = fmaxf(cm, __shfl_xor(cm, 16));
    cm = fmaxf(cm, __shfl_xor(cm, 32));
    const float mn = fmaxf(mrun, cm);
    const float scl = exp2f(K2 * (mrun - mn));  // 0 on first chunk
    mrun = mn;
    // P = exp2(K2*(S-m)) -> f16 slice; sum
    float cs = 0.f;
#pragma unroll
    for (int kt = 0; kt < 4; ++kt)
#pragma unroll
      for (int j = 0; j < 4; ++j) {
        float p = exp2f(K2 * (sa[kt][j] - mn));
        cs += p;
        psl[l16 * 72 + kt * 16 + 4 * g + j] = (_Float16)p;
      }
    cs += __shfl_xor(cs, 16);
    cs += __shfl_xor(cs, 32);
    srun = srun * scl + cs;
#pragma unroll
    for (int ht = 0; ht < 4; ++ht) O[ht] *= scl;
    // make P writes visible to this wave's reads, defeat MFMA hoisting
    asm volatile("s_waitcnt lgkmcnt(0)" ::: "memory");
    __builtin_amdgcn_sched_barrier(0);
    // PV: O^T[h][qr] += v^T[h][k] * P^T[k][qr]
#pragma unroll
    for (int ks2 = 0; ks2 < 2; ++ks2) {
      f16x8 bp = *(const f16x8*)&psl[l16 * 72 + ks2 * 32 + g * 8];
#pragma unroll
      for (int ht = 0; ht < 4; ++ht) {
        f16x8 av = *(const f16x8*)&vT[(ht * 16 + l16) * 264 + kb + ks2 * 32 + g * 8];
        __builtin_amdgcn_s_setprio(1);
        O[ht] = MFMA16(av, bp, O[ht]);
        __builtin_amdgcn_s_setprio(0);
      }
    }
  }

  // ---- output: out[qr][h] = O^T[h][qr] / srun ----
  const float inv = 1.0f / srun;
#pragma unroll
  for (int ht = 0; ht < 4; ++ht) {
    f32x4 r = O[ht] * inv;
    *(f32x4*)&out[((size_t)b * 256 + qr) * 64 + ht * 16 + 4 * g] = r;
  }
}

// ---------------------------------------------------------------------------
extern "C" void kernel_launch(void* const* d_in, const int* in_sizes, int n_in,
                              void* d_out, int out_size, void* d_ws, size_t ws_size,
                              hipStream_t stream) {
  const float* x  = (const float*)d_in[0];
  const float* Wq = (const float*)d_in[1];
  const float* Wk = (const float*)d_in[2];
  const float* Wv = (const float*)d_in[3];

  _Float16* wstg = (_Float16*)d_ws;  // 12*1536*16B = 294912 B

  wprep_kernel<<<72, 256, 0, stream>>>(Wq, Wk, Wv, wstg);
  fused_kernel<<<512, 1024, 0, stream>>>(x, wstg, (float*)d_out);
}